// Round 1
// baseline (279.632 us; speedup 1.0000x reference)
//
#include <hip/hip_runtime.h>
#include <hip/hip_bf16.h>
#include <stdint.h>

#define NR 384          // total rows
#define DD 73728        // C*H*W
#define PDV 16          // N_PARTS * N_DATASETS
#define BSV 192         // batch size
#define KSPLIT 64       // split-K factor
#define KCH 1152        // DD / KSPLIT
#define BK 64           // K-tile per iteration

typedef __bf16 bf16;
typedef __attribute__((ext_vector_type(8))) __bf16 bf16x8;
typedef __attribute__((ext_vector_type(4))) float f32x4;

// ---------------------------------------------------------------- async 16B
__device__ __forceinline__ void async_copy16(const bf16* g, bf16* l) {
    __builtin_amdgcn_global_load_lds(
        (__attribute__((address_space(1))) void*)g,
        (__attribute__((address_space(3))) void*)l,
        16, 0, 0);
}

// ---------------------------------------------------------------- kernel 1
// Z[row][col] = bf16(X[row][col] - M[(row/4)%4][col]); 8 elems/thread.
// 36 blocks per row (36*256*8 = 73728).
__global__ __launch_bounds__(256) void k_demean(const float* __restrict__ X,
                                                const float* __restrict__ M,
                                                bf16* __restrict__ Z) {
    int bx  = blockIdx.x;
    int row = bx / 36;
    int cb  = bx - row * 36;
    int col = (cb << 11) + (threadIdx.x << 3);
    int ds  = (row >> 2) & 3;
    size_t e = (size_t)row * DD + col;
    const float4* xp = (const float4*)(X + e);
    const float4* mp = (const float4*)(M + (size_t)ds * DD + col);
    float4 x0 = xp[0], x1 = xp[1];
    float4 m0 = mp[0], m1 = mp[1];
    bf16x8 z;
    z[0] = (bf16)(x0.x - m0.x);
    z[1] = (bf16)(x0.y - m0.y);
    z[2] = (bf16)(x0.z - m0.z);
    z[3] = (bf16)(x0.w - m0.w);
    z[4] = (bf16)(x1.x - m1.x);
    z[5] = (bf16)(x1.y - m1.y);
    z[6] = (bf16)(x1.z - m1.z);
    z[7] = (bf16)(x1.w - m1.w);
    *(bf16x8*)(Z + e) = z;
}

// ---------------------------------------------------------------- kernel 2
// G (fp32, upper-tile-triangle valid) += Z * Z^T over this block's K chunk.
// 6 tiles (128x128) * KSPLIT blocks. 256 thr = 4 waves in 2x2, each wave
// 64x64 = 4x4 mfma_f32_16x16x32_bf16 tiles. LDS layout [128][64] bf16 with
// 16B-segment XOR-by-(row&7) swizzle (global_load_lds forbids padding).
__global__ __launch_bounds__(256) void k_gram(const bf16* __restrict__ Z,
                                              float* __restrict__ G) {
    __shared__ bf16 ash[128 * BK];
    __shared__ bf16 bsh[128 * BK];
    const int tid  = threadIdx.x;
    const int lane = tid & 63;
    const int w    = tid >> 6;
    const int quad = lane >> 4;
    const int l15  = lane & 15;
    const int wm   = w & 1, wn = w >> 1;

    int bx   = blockIdx.x;
    int tile = bx % 6;          // same-tile blocks land on nearby CUs
    int ks   = bx / 6;
    // tiles: (0,0),(0,1),(0,2),(1,1),(1,2),(2,2)
    int tm = (tile < 3) ? 0 : ((tile < 5) ? 1 : 2);
    int tn = (tile < 3) ? tile : ((tile < 5) ? (tile - 2) : 2);
    int rowA0 = tm * 128, rowB0 = tn * 128;
    size_t k0 = (size_t)ks * KCH;

    f32x4 acc[4][4];
#pragma unroll
    for (int i = 0; i < 4; ++i)
#pragma unroll
        for (int j = 0; j < 4; ++j) acc[i][j] = (f32x4){0.f, 0.f, 0.f, 0.f};

    for (int kb = 0; kb < KCH; kb += BK) {
        size_t kbase = k0 + kb;
        __syncthreads();   // previous iter's ds_reads done before overwrite
#pragma unroll
        for (int t = 0; t < 4; ++t) {
            int S   = t * 256 + tid;
            int row = S >> 3;
            int sp  = S & 7;            // LDS 16B segment within row
            int gs  = sp ^ (row & 7);   // swizzled global segment
            size_t gco = kbase + gs * 8;
            int ldsoff = (t * 256 + w * 64) * 8;   // wave-uniform base
            async_copy16(Z + (size_t)(rowA0 + row) * DD + gco, &ash[ldsoff]);
            async_copy16(Z + (size_t)(rowB0 + row) * DD + gco, &bsh[ldsoff]);
        }
        __syncthreads();   // includes vmcnt(0) drain of global_load_lds

#pragma unroll
        for (int kk = 0; kk < BK; kk += 32) {
            int sgi = (kk >> 5) * 4 + quad;
            bf16x8 af[4], bfv[4];
#pragma unroll
            for (int i = 0; i < 4; ++i) {
                int r = wm * 64 + i * 16 + l15;
                af[i] = *(const bf16x8*)&ash[r * BK + ((sgi ^ (r & 7)) << 3)];
            }
#pragma unroll
            for (int j = 0; j < 4; ++j) {
                int r = wn * 64 + j * 16 + l15;
                bfv[j] = *(const bf16x8*)&bsh[r * BK + ((sgi ^ (r & 7)) << 3)];
            }
#pragma unroll
            for (int i = 0; i < 4; ++i)
#pragma unroll
                for (int j = 0; j < 4; ++j)
                    acc[i][j] = __builtin_amdgcn_mfma_f32_16x16x32_bf16(
                        af[i], bfv[j], acc[i][j], 0, 0, 0);
        }
    }

    // epilogue: C/D layout col=lane&15, row=quad*4+reg  (m89/m91 verified)
#pragma unroll
    for (int i = 0; i < 4; ++i) {
        int grow0 = rowA0 + wm * 64 + i * 16 + quad * 4;
#pragma unroll
        for (int j = 0; j < 4; ++j) {
            int gcol = rowB0 + wn * 64 + j * 16 + l15;
#pragma unroll
            for (int r = 0; r < 4; ++r)
                atomicAdd(&G[(size_t)(grow0 + r) * NR + gcol], acc[i][j][r]);
        }
    }
}

// ---------------------------------------------------------------- kernel 3
__device__ __forceinline__ float sym_g(const float* __restrict__ G, int a, int b) {
    return (a <= b) ? G[(size_t)a * NR + b] : G[(size_t)b * NR + a];
}

__device__ __forceinline__ float pairloss(const float* __restrict__ G,
                                          const float* invn, const float* Ds,
                                          int a, int b) {
    float num = sym_g(G, a, b) * invn[a] * invn[b] * 10.0f;  // 1/TEMP
    float en  = expf(num);
    return -(num - logf(en + Ds[a])) - (num - logf(en + Ds[b]));
}

__global__ __launch_bounds__(1024) void k_loss(const float* __restrict__ G,
                                               float* __restrict__ out) {
    __shared__ float invn[NR];
    __shared__ float Ds[NR];
    __shared__ float wred[16];
    const int tid  = threadIdx.x;
    const int lane = tid & 63;
    const int w    = tid >> 6;

    for (int a = tid; a < NR; a += 1024)
        invn[a] = 1.0f / fmaxf(sqrtf(G[(size_t)a * NR + a]), 1e-6f);
    __syncthreads();

    for (int a = w; a < NR; a += 16) {     // 16 waves, 24 rows each
        float ia  = invn[a];
        int arem  = a & 15;
        float acc = 0.0f;
        for (int b = lane; b < NR; b += 64) {
            float s = sym_g(G, a, b) * ia * invn[b] * 10.0f;
            if ((b & 15) != arem) acc += expf(s);
        }
#pragma unroll
        for (int o = 32; o > 0; o >>= 1) acc += __shfl_down(acc, o);
        if (lane == 0) Ds[a] = acc;
    }
    __syncthreads();

    float c = 0.0f;
    if (tid < BSV) {
        int p = tid;
        int i1 = p, i2 = BSV + p;
        int i3 = (p + PDV) % NR, i4 = (BSV + p + PDV) % NR;
        c = pairloss(G, invn, Ds, i1, i2) + pairloss(G, invn, Ds, i3, i4)
          + pairloss(G, invn, Ds, i1, i3) + pairloss(G, invn, Ds, i2, i4);
    }
#pragma unroll
    for (int o = 32; o > 0; o >>= 1) c += __shfl_down(c, o);
    if (lane == 0) wred[w] = c;
    __syncthreads();
    if (tid == 0) {
        float tot = 0.0f;
#pragma unroll
        for (int i = 0; i < 16; ++i) tot += wred[i];
        out[0] = tot / 576.0f;   // N_TRANSFORMS * 3 * BS
    }
}

// ---------------------------------------------------------------- launch
extern "C" void kernel_launch(void* const* d_in, const int* in_sizes, int n_in,
                              void* d_out, int out_size, void* d_ws, size_t ws_size,
                              hipStream_t stream) {
    const float* X = (const float*)d_in[0];
    const float* M = (const float*)d_in[1];
    float* out = (float*)d_out;

    bf16*  Z = (bf16*)d_ws;                                    // 384*73728*2 B
    float* G = (float*)((char*)d_ws + (size_t)NR * DD * 2);    // 384*384*4 B

    hipMemsetAsync(G, 0, (size_t)NR * NR * sizeof(float), stream);
    k_demean<<<dim3(NR * 36), dim3(256), 0, stream>>>(X, M, Z);
    k_gram<<<dim3(6 * KSPLIT), dim3(256), 0, stream>>>(Z, G);
    k_loss<<<dim3(1), dim3(1024), 0, stream>>>(G, out);
}

// Round 2
// 224.022 us; speedup vs baseline: 1.2482x; 1.2482x over previous
//
#include <hip/hip_runtime.h>
#include <hip/hip_bf16.h>
#include <stdint.h>

#define NR 384          // total rows
#define DD 73728        // C*H*W
#define PDV 16          // N_PARTS * N_DATASETS
#define BSV 192         // batch size
#define KSPLIT 64       // split-K factor
#define KCH 1152        // DD / KSPLIT
#define BK 64           // K-tile per iteration

typedef __bf16 bf16;
typedef __attribute__((ext_vector_type(8))) __bf16 bf16x8;
typedef __attribute__((ext_vector_type(4))) float f32x4;

// ---------------------------------------------------------------- async 16B
__device__ __forceinline__ void async_copy16(const bf16* g, bf16* l) {
    __builtin_amdgcn_global_load_lds(
        (__attribute__((address_space(1))) void*)g,
        (__attribute__((address_space(3))) void*)l,
        16, 0, 0);
}

// ---------------------------------------------------------------- kernel 1
// Z[row][col] = bf16(X[row][col] - M[(row/4)%4][col]); 8 elems/thread.
__global__ __launch_bounds__(256) void k_demean(const float* __restrict__ X,
                                                const float* __restrict__ M,
                                                bf16* __restrict__ Z) {
    int bx  = blockIdx.x;
    int row = bx / 36;
    int cb  = bx - row * 36;
    int col = (cb << 11) + (threadIdx.x << 3);
    int ds  = (row >> 2) & 3;
    size_t e = (size_t)row * DD + col;
    const float4* xp = (const float4*)(X + e);
    const float4* mp = (const float4*)(M + (size_t)ds * DD + col);
    float4 x0 = xp[0], x1 = xp[1];
    float4 m0 = mp[0], m1 = mp[1];
    bf16x8 z;
    z[0] = (bf16)(x0.x - m0.x);
    z[1] = (bf16)(x0.y - m0.y);
    z[2] = (bf16)(x0.z - m0.z);
    z[3] = (bf16)(x0.w - m0.w);
    z[4] = (bf16)(x1.x - m1.x);
    z[5] = (bf16)(x1.y - m1.y);
    z[6] = (bf16)(x1.z - m1.z);
    z[7] = (bf16)(x1.w - m1.w);
    *(bf16x8*)(Z + e) = z;
}

// ---------------------------------------------------------------- kernel 2
// G (fp32, upper-tile-triangle valid) += Z * Z^T over this block's K chunk.
__global__ __launch_bounds__(256) void k_gram(const bf16* __restrict__ Z,
                                              float* __restrict__ G) {
    __shared__ bf16 ash[128 * BK];
    __shared__ bf16 bsh[128 * BK];
    const int tid  = threadIdx.x;
    const int lane = tid & 63;
    const int w    = tid >> 6;
    const int quad = lane >> 4;
    const int l15  = lane & 15;
    const int wm   = w & 1, wn = w >> 1;

    int bx   = blockIdx.x;
    int tile = bx % 6;
    int ks   = bx / 6;
    int tm = (tile < 3) ? 0 : ((tile < 5) ? 1 : 2);
    int tn = (tile < 3) ? tile : ((tile < 5) ? (tile - 2) : 2);
    int rowA0 = tm * 128, rowB0 = tn * 128;
    size_t k0 = (size_t)ks * KCH;

    f32x4 acc[4][4];
#pragma unroll
    for (int i = 0; i < 4; ++i)
#pragma unroll
        for (int j = 0; j < 4; ++j) acc[i][j] = (f32x4){0.f, 0.f, 0.f, 0.f};

    for (int kb = 0; kb < KCH; kb += BK) {
        size_t kbase = k0 + kb;
        __syncthreads();
#pragma unroll
        for (int t = 0; t < 4; ++t) {
            int S   = t * 256 + tid;
            int row = S >> 3;
            int sp  = S & 7;
            int gs  = sp ^ (row & 7);
            size_t gco = kbase + gs * 8;
            int ldsoff = (t * 256 + w * 64) * 8;
            async_copy16(Z + (size_t)(rowA0 + row) * DD + gco, &ash[ldsoff]);
            async_copy16(Z + (size_t)(rowB0 + row) * DD + gco, &bsh[ldsoff]);
        }
        __syncthreads();

#pragma unroll
        for (int kk = 0; kk < BK; kk += 32) {
            int sgi = (kk >> 5) * 4 + quad;
            bf16x8 af[4], bfv[4];
#pragma unroll
            for (int i = 0; i < 4; ++i) {
                int r = wm * 64 + i * 16 + l15;
                af[i] = *(const bf16x8*)&ash[r * BK + ((sgi ^ (r & 7)) << 3)];
            }
#pragma unroll
            for (int j = 0; j < 4; ++j) {
                int r = wn * 64 + j * 16 + l15;
                bfv[j] = *(const bf16x8*)&bsh[r * BK + ((sgi ^ (r & 7)) << 3)];
            }
#pragma unroll
            for (int i = 0; i < 4; ++i)
#pragma unroll
                for (int j = 0; j < 4; ++j)
                    acc[i][j] = __builtin_amdgcn_mfma_f32_16x16x32_bf16(
                        af[i], bfv[j], acc[i][j], 0, 0, 0);
        }
    }

#pragma unroll
    for (int i = 0; i < 4; ++i) {
        int grow0 = rowA0 + wm * 64 + i * 16 + quad * 4;
#pragma unroll
        for (int j = 0; j < 4; ++j) {
            int gcol = rowB0 + wn * 64 + j * 16 + l15;
#pragma unroll
            for (int r = 0; r < 4; ++r)
                atomicAdd(&G[(size_t)(grow0 + r) * NR + gcol], acc[i][j][r]);
        }
    }
}

// ---------------------------------------------------------------- kernel 3a
// Mirror upper triangle into lower (full symmetric G) + per-row inv-norm.
// Block a handles row a. Reads G[b][a] (column, L2-resident), writes row a.
__global__ __launch_bounds__(256) void k_symm(float* __restrict__ G,
                                              float* __restrict__ invn) {
    int a = blockIdx.x;
    if (threadIdx.x == 0)
        invn[a] = 1.0f / fmaxf(sqrtf(G[(size_t)a * NR + a]), 1e-6f);
    for (int b = threadIdx.x; b < a; b += 256)
        G[(size_t)a * NR + b] = G[(size_t)b * NR + a];
}

// ---------------------------------------------------------------- kernel 3b
// One wave per row: Ds[a] = sum_b mask * exp(G[a][b]*invn[a]*invn[b]*10).
__global__ __launch_bounds__(256) void k_dsum(const float* __restrict__ G,
                                              const float* __restrict__ invn,
                                              float* __restrict__ Ds) {
    const int lane = threadIdx.x & 63;
    const int a    = blockIdx.x * 4 + (threadIdx.x >> 6);
    float ia  = invn[a];
    int arem  = a & 15;
    float acc = 0.0f;
    for (int b = lane; b < NR; b += 64) {
        float s = G[(size_t)a * NR + b] * ia * invn[b] * 10.0f;
        if ((b & 15) != arem) acc += expf(s);
    }
#pragma unroll
    for (int o = 32; o > 0; o >>= 1) acc += __shfl_down(acc, o);
    if (lane == 0) Ds[a] = acc;
}

// ---------------------------------------------------------------- kernel 3c
__device__ __forceinline__ float pairloss(const float* __restrict__ G,
                                          const float* __restrict__ invn,
                                          const float* __restrict__ Ds,
                                          int a, int b) {
    float num = G[(size_t)a * NR + b] * invn[a] * invn[b] * 10.0f;
    float en  = expf(num);
    return -(num - logf(en + Ds[a])) - (num - logf(en + Ds[b]));
}

__global__ __launch_bounds__(256) void k_final(const float* __restrict__ G,
                                               const float* __restrict__ invn,
                                               const float* __restrict__ Ds,
                                               float* __restrict__ out) {
    __shared__ float wred[4];
    const int tid  = threadIdx.x;
    const int lane = tid & 63;
    const int w    = tid >> 6;
    float c = 0.0f;
    if (tid < BSV) {
        int p = tid;
        int i1 = p, i2 = BSV + p;
        int i3 = (p + PDV) % NR, i4 = (BSV + p + PDV) % NR;
        c = pairloss(G, invn, Ds, i1, i2) + pairloss(G, invn, Ds, i3, i4)
          + pairloss(G, invn, Ds, i1, i3) + pairloss(G, invn, Ds, i2, i4);
    }
#pragma unroll
    for (int o = 32; o > 0; o >>= 1) c += __shfl_down(c, o);
    if (lane == 0) wred[w] = c;
    __syncthreads();
    if (tid == 0) {
        float tot = wred[0] + wred[1] + wred[2] + wred[3];
        out[0] = tot / 576.0f;   // N_TRANSFORMS * 3 * BS
    }
}

// ---------------------------------------------------------------- launch
extern "C" void kernel_launch(void* const* d_in, const int* in_sizes, int n_in,
                              void* d_out, int out_size, void* d_ws, size_t ws_size,
                              hipStream_t stream) {
    const float* X = (const float*)d_in[0];
    const float* M = (const float*)d_in[1];
    float* out = (float*)d_out;

    char* ws = (char*)d_ws;
    bf16*  Z    = (bf16*)ws;                                  // 56.6 MB
    float* G    = (float*)(ws + (size_t)NR * DD * 2);         // 590 KB
    float* invn = (float*)(ws + (size_t)NR * DD * 2 + (size_t)NR * NR * 4);
    float* Ds   = invn + NR;

    hipMemsetAsync(G, 0, (size_t)NR * NR * sizeof(float), stream);
    k_demean<<<dim3(NR * 36), dim3(256), 0, stream>>>(X, M, Z);
    k_gram<<<dim3(6 * KSPLIT), dim3(256), 0, stream>>>(Z, G);
    k_symm<<<dim3(NR), dim3(256), 0, stream>>>(G, invn);
    k_dsum<<<dim3(NR / 4), dim3(256), 0, stream>>>(G, invn, Ds);
    k_final<<<dim3(1), dim3(256), 0, stream>>>(G, invn, Ds, out);
}

// Round 3
// 214.261 us; speedup vs baseline: 1.3051x; 1.0456x over previous
//
#include <hip/hip_runtime.h>
#include <hip/hip_bf16.h>
#include <stdint.h>

#define NR 384          // total rows
#define DD 73728        // C*H*W
#define PDV 16          // N_PARTS * N_DATASETS
#define BSV 192         // batch size
#define KSPLIT 128      // split-K factor (768 blocks = 3/CU exactly)
#define KCH 576         // DD / KSPLIT
#define BK 64           // K-tile per iteration

typedef __bf16 bf16;
typedef __attribute__((ext_vector_type(8))) __bf16 bf16x8;
typedef __attribute__((ext_vector_type(4))) float f32x4;

// ---------------------------------------------------------------- async 16B
__device__ __forceinline__ void async_copy16(const bf16* g, bf16* l) {
    __builtin_amdgcn_global_load_lds(
        (__attribute__((address_space(1))) void*)g,
        (__attribute__((address_space(3))) void*)l,
        16, 0, 0);
}

// ---------------------------------------------------------------- kernel 1
// Z[row][col] = bf16(X[row][col] - M[(row/4)%4][col]); 8 elems/thread.
__global__ __launch_bounds__(256) void k_demean(const float* __restrict__ X,
                                                const float* __restrict__ M,
                                                bf16* __restrict__ Z) {
    int bx  = blockIdx.x;
    int row = bx / 36;
    int cb  = bx - row * 36;
    int col = (cb << 11) + (threadIdx.x << 3);
    int ds  = (row >> 2) & 3;
    size_t e = (size_t)row * DD + col;
    const float4* xp = (const float4*)(X + e);
    const float4* mp = (const float4*)(M + (size_t)ds * DD + col);
    float4 x0 = xp[0], x1 = xp[1];
    float4 m0 = mp[0], m1 = mp[1];
    bf16x8 z;
    z[0] = (bf16)(x0.x - m0.x);
    z[1] = (bf16)(x0.y - m0.y);
    z[2] = (bf16)(x0.z - m0.z);
    z[3] = (bf16)(x0.w - m0.w);
    z[4] = (bf16)(x1.x - m1.x);
    z[5] = (bf16)(x1.y - m1.y);
    z[6] = (bf16)(x1.z - m1.z);
    z[7] = (bf16)(x1.w - m1.w);
    *(bf16x8*)(Z + e) = z;
}

// ---------------------------------------------------------------- kernel 2
// Partial Gram: Gp[ks][tile][128][128] = Z_tile * Z_tile^T over K chunk ks.
// Plain coalesced stores — no atomics, no G memset needed.
__global__ __launch_bounds__(256) void k_gram(const bf16* __restrict__ Z,
                                              float* __restrict__ Gp) {
    __shared__ bf16 ash[128 * BK];
    __shared__ bf16 bsh[128 * BK];
    const int tid  = threadIdx.x;
    const int lane = tid & 63;
    const int w    = tid >> 6;
    const int quad = lane >> 4;
    const int l15  = lane & 15;
    const int wm   = w & 1, wn = w >> 1;

    int bx   = blockIdx.x;
    int tile = bx % 6;
    int ks   = bx / 6;
    int tm = (tile < 3) ? 0 : ((tile < 5) ? 1 : 2);
    int tn = (tile < 3) ? tile : ((tile < 5) ? (tile - 2) : 2);
    int rowA0 = tm * 128, rowB0 = tn * 128;
    size_t k0 = (size_t)ks * KCH;

    f32x4 acc[4][4];
#pragma unroll
    for (int i = 0; i < 4; ++i)
#pragma unroll
        for (int j = 0; j < 4; ++j) acc[i][j] = (f32x4){0.f, 0.f, 0.f, 0.f};

    for (int kb = 0; kb < KCH; kb += BK) {
        size_t kbase = k0 + kb;
        __syncthreads();
#pragma unroll
        for (int t = 0; t < 4; ++t) {
            int S   = t * 256 + tid;
            int row = S >> 3;
            int sp  = S & 7;
            int gs  = sp ^ (row & 7);
            size_t gco = kbase + gs * 8;
            int ldsoff = (t * 256 + w * 64) * 8;
            async_copy16(Z + (size_t)(rowA0 + row) * DD + gco, &ash[ldsoff]);
            async_copy16(Z + (size_t)(rowB0 + row) * DD + gco, &bsh[ldsoff]);
        }
        __syncthreads();

#pragma unroll
        for (int kk = 0; kk < BK; kk += 32) {
            int sgi = (kk >> 5) * 4 + quad;
            bf16x8 af[4], bfv[4];
#pragma unroll
            for (int i = 0; i < 4; ++i) {
                int r = wm * 64 + i * 16 + l15;
                af[i] = *(const bf16x8*)&ash[r * BK + ((sgi ^ (r & 7)) << 3)];
            }
#pragma unroll
            for (int j = 0; j < 4; ++j) {
                int r = wn * 64 + j * 16 + l15;
                bfv[j] = *(const bf16x8*)&bsh[r * BK + ((sgi ^ (r & 7)) << 3)];
            }
#pragma unroll
            for (int i = 0; i < 4; ++i)
#pragma unroll
                for (int j = 0; j < 4; ++j)
                    acc[i][j] = __builtin_amdgcn_mfma_f32_16x16x32_bf16(
                        af[i], bfv[j], acc[i][j], 0, 0, 0);
        }
    }

    float* gp = Gp + ((size_t)(ks * 6 + tile) << 14);
#pragma unroll
    for (int i = 0; i < 4; ++i) {
        int lr0 = wm * 64 + i * 16 + quad * 4;
#pragma unroll
        for (int j = 0; j < 4; ++j) {
            int lc = wn * 64 + j * 16 + l15;
#pragma unroll
            for (int r = 0; r < 4; ++r)
                gp[(lr0 + r) * 128 + lc] = acc[i][j][r];
        }
    }
}

// ---------------------------------------------------------------- kernel 3
// Reduce partials -> full symmetric G + per-row inverse norm.
// One thread per (tile, lr, lc): 98304 threads, coalesced stride-6*16K loads.
__global__ __launch_bounds__(256) void k_red(const float* __restrict__ Gp,
                                             float* __restrict__ G,
                                             float* __restrict__ invn) {
    int t    = blockIdx.x * 256 + threadIdx.x;
    int tile = t >> 14;
    int idx  = t & 16383;
    int lr   = idx >> 7, lc = idx & 127;
    const float* p = Gp + ((size_t)tile << 14) + idx;
    float s = 0.0f;
#pragma unroll 8
    for (int ks = 0; ks < KSPLIT; ++ks) s += p[(size_t)ks * 98304];
    int tm = (tile < 3) ? 0 : ((tile < 5) ? 1 : 2);
    int tn = (tile < 3) ? tile : ((tile < 5) ? (tile - 2) : 2);
    int a = tm * 128 + lr, b = tn * 128 + lc;
    G[(size_t)a * NR + b] = s;
    G[(size_t)b * NR + a] = s;
    if (a == b) invn[a] = 1.0f / fmaxf(sqrtf(s), 1e-6f);
}

// ---------------------------------------------------------------- kernel 4
// One wave per row: Ds[a] = sum_b mask * exp(G[a][b]*invn[a]*invn[b]*10).
__global__ __launch_bounds__(256) void k_dsum(const float* __restrict__ G,
                                              const float* __restrict__ invn,
                                              float* __restrict__ Ds) {
    const int lane = threadIdx.x & 63;
    const int a    = blockIdx.x * 4 + (threadIdx.x >> 6);
    float ia  = invn[a];
    int arem  = a & 15;
    float acc = 0.0f;
    for (int b = lane; b < NR; b += 64) {
        float s = G[(size_t)a * NR + b] * ia * invn[b] * 10.0f;
        if ((b & 15) != arem) acc += expf(s);
    }
#pragma unroll
    for (int o = 32; o > 0; o >>= 1) acc += __shfl_down(acc, o);
    if (lane == 0) Ds[a] = acc;
}

// ---------------------------------------------------------------- kernel 5
__device__ __forceinline__ float pairloss(const float* __restrict__ G,
                                          const float* __restrict__ invn,
                                          const float* __restrict__ Ds,
                                          int a, int b) {
    float num = G[(size_t)a * NR + b] * invn[a] * invn[b] * 10.0f;
    float en  = expf(num);
    return -(num - logf(en + Ds[a])) - (num - logf(en + Ds[b]));
}

__global__ __launch_bounds__(256) void k_final(const float* __restrict__ G,
                                               const float* __restrict__ invn,
                                               const float* __restrict__ Ds,
                                               float* __restrict__ out) {
    __shared__ float wred[4];
    const int tid  = threadIdx.x;
    const int lane = tid & 63;
    const int w    = tid >> 6;
    float c = 0.0f;
    if (tid < BSV) {
        int p = tid;
        int i1 = p, i2 = BSV + p;
        int i3 = (p + PDV) % NR, i4 = (BSV + p + PDV) % NR;
        c = pairloss(G, invn, Ds, i1, i2) + pairloss(G, invn, Ds, i3, i4)
          + pairloss(G, invn, Ds, i1, i3) + pairloss(G, invn, Ds, i2, i4);
    }
#pragma unroll
    for (int o = 32; o > 0; o >>= 1) c += __shfl_down(c, o);
    if (lane == 0) wred[w] = c;
    __syncthreads();
    if (tid == 0) {
        float tot = wred[0] + wred[1] + wred[2] + wred[3];
        out[0] = tot / 576.0f;   // N_TRANSFORMS * 3 * BS
    }
}

// ---------------------------------------------------------------- launch
extern "C" void kernel_launch(void* const* d_in, const int* in_sizes, int n_in,
                              void* d_out, int out_size, void* d_ws, size_t ws_size,
                              hipStream_t stream) {
    const float* X = (const float*)d_in[0];
    const float* M = (const float*)d_in[1];
    float* out = (float*)d_out;

    char* ws = (char*)d_ws;
    bf16*  Z    = (bf16*)ws;                                   // 56.6 MB
    float* Gp   = (float*)(ws + (size_t)NR * DD * 2);          // 50.3 MB
    float* G    = Gp + (size_t)KSPLIT * 6 * 16384;             // 590 KB
    float* invn = G + (size_t)NR * NR;
    float* Ds   = invn + NR;

    k_demean<<<dim3(NR * 36), dim3(256), 0, stream>>>(X, M, Z);
    k_gram<<<dim3(6 * KSPLIT), dim3(256), 0, stream>>>(Z, Gp);
    k_red<<<dim3(384), dim3(256), 0, stream>>>(Gp, G, invn);
    k_dsum<<<dim3(NR / 4), dim3(256), 0, stream>>>(G, invn, Ds);
    k_final<<<dim3(1), dim3(256), 0, stream>>>(G, invn, Ds, out);
}

// Round 4
// 199.530 us; speedup vs baseline: 1.4015x; 1.0738x over previous
//
#include <hip/hip_runtime.h>
#include <hip/hip_bf16.h>
#include <stdint.h>

#define NR 384          // total rows
#define DD 73728        // C*H*W
#define PDV 16          // N_PARTS * N_DATASETS
#define BSV 192         // batch size
#define KSPLIT 128      // split-K factor (768 blocks = 3/CU)
#define KCH 576         // DD / KSPLIT
#define BK 32           // K-tile per iteration (fp32 staging)

typedef __bf16 bf16;
typedef __attribute__((ext_vector_type(8))) __bf16 bf16x8;
typedef __attribute__((ext_vector_type(4))) float f32x4;

// ---------------------------------------------------------------- async 16B
__device__ __forceinline__ void async_copy16(const float* g, float* l) {
    __builtin_amdgcn_global_load_lds(
        (__attribute__((address_space(1))) void*)g,
        (__attribute__((address_space(3))) void*)l,
        16, 0, 0);
}

// ---------------------------------------------------------------- kernel 1
// Fused demean + cast + partial Gram.
// Gp[ks][tile][128][128] = (X-M)_tileA * (X-M)_tileB^T over K chunk ks.
// fp32 X staged via global_load_lds with XOR-by-(row&7) 16B-segment swizzle;
// demean + bf16 convert at fragment-read time (ds = (lane&15)>>2 for ALL
// fragments since row = w*64+i*16+l15 and everything but l15 is 0 mod 4).
__global__ __launch_bounds__(256) void k_gram(const float* __restrict__ X,
                                              const float* __restrict__ M,
                                              float* __restrict__ Gp) {
    __shared__ float ashF[128 * BK];   // 16 KB
    __shared__ float bshF[128 * BK];   // 16 KB
    __shared__ float msh[4 * BK];      // 512 B
    const int tid  = threadIdx.x;
    const int lane = tid & 63;
    const int w    = tid >> 6;
    const int quad = lane >> 4;
    const int l15  = lane & 15;
    const int l7   = lane & 7;
    const int wm   = w & 1, wn = w >> 1;

    int bx   = blockIdx.x;
    int tile = bx % 6;
    int ks   = bx / 6;
    int tm = (tile < 3) ? 0 : ((tile < 5) ? 1 : 2);
    int tn = (tile < 3) ? tile : ((tile < 5) ? (tile - 2) : 2);
    int rowA0 = tm * 128, rowB0 = tn * 128;
    size_t k0 = (size_t)ks * KCH;

    f32x4 acc[4][4];
#pragma unroll
    for (int i = 0; i < 4; ++i)
#pragma unroll
        for (int j = 0; j < 4; ++j) acc[i][j] = (f32x4){0.f, 0.f, 0.f, 0.f};

    for (int kb = 0; kb < KCH; kb += BK) {   // 18 iterations
        size_t kbase = k0 + kb;
        __syncthreads();   // prior iter's LDS reads done before overwrite
#pragma unroll
        for (int t = 0; t < 4; ++t) {
            int S   = t * 256 + tid;
            int row = S >> 3;
            int sp  = S & 7;            // LDS 16B segment within row
            int gs  = sp ^ (row & 7);   // swizzled global segment
            size_t gco = kbase + gs * 4;
            int base = (t * 256 + w * 64) * 4;   // wave-uniform float offset
            async_copy16(X + (size_t)(rowA0 + row) * DD + gco, &ashF[base]);
            async_copy16(X + (size_t)(rowB0 + row) * DD + gco, &bshF[base]);
        }
        if (tid < 32) {   // 4 datasets x 32 floats of M, unswizzled
            float4 m4 = *(const float4*)(M + (size_t)(tid >> 3) * DD + kbase + (tid & 7) * 4);
            *(float4*)&msh[tid * 4] = m4;
        }
        __syncthreads();   // drains global_load_lds (vmcnt) + ds_write

        // per-lane mean fragment, shared by all 8 A/B fragments
        f32x4 mu = *(const f32x4*)&msh[(l15 >> 2) * BK + quad * 8];
        f32x4 mv = *(const f32x4*)&msh[(l15 >> 2) * BK + quad * 8 + 4];

        bf16x8 af[4], bfv[4];
#pragma unroll
        for (int i = 0; i < 4; ++i) {
            int r = wm * 64 + i * 16 + l15;
            f32x4 u = *(const f32x4*)&ashF[r * BK + (((quad << 1) ^ l7) << 2)];
            f32x4 v = *(const f32x4*)&ashF[r * BK + ((((quad << 1) | 1) ^ l7) << 2)];
            bf16x8 f;
            f[0] = (bf16)(u[0] - mu[0]); f[1] = (bf16)(u[1] - mu[1]);
            f[2] = (bf16)(u[2] - mu[2]); f[3] = (bf16)(u[3] - mu[3]);
            f[4] = (bf16)(v[0] - mv[0]); f[5] = (bf16)(v[1] - mv[1]);
            f[6] = (bf16)(v[2] - mv[2]); f[7] = (bf16)(v[3] - mv[3]);
            af[i] = f;
        }
#pragma unroll
        for (int j = 0; j < 4; ++j) {
            int r = wn * 64 + j * 16 + l15;
            f32x4 u = *(const f32x4*)&bshF[r * BK + (((quad << 1) ^ l7) << 2)];
            f32x4 v = *(const f32x4*)&bshF[r * BK + ((((quad << 1) | 1) ^ l7) << 2)];
            bf16x8 f;
            f[0] = (bf16)(u[0] - mu[0]); f[1] = (bf16)(u[1] - mu[1]);
            f[2] = (bf16)(u[2] - mu[2]); f[3] = (bf16)(u[3] - mu[3]);
            f[4] = (bf16)(v[0] - mv[0]); f[5] = (bf16)(v[1] - mv[1]);
            f[6] = (bf16)(v[2] - mv[2]); f[7] = (bf16)(v[3] - mv[3]);
            bfv[j] = f;
        }
#pragma unroll
        for (int i = 0; i < 4; ++i)
#pragma unroll
            for (int j = 0; j < 4; ++j)
                acc[i][j] = __builtin_amdgcn_mfma_f32_16x16x32_bf16(
                    af[i], bfv[j], acc[i][j], 0, 0, 0);
    }

    float* gp = Gp + ((size_t)(ks * 6 + tile) << 14);
#pragma unroll
    for (int i = 0; i < 4; ++i) {
        int lr0 = wm * 64 + i * 16 + quad * 4;
#pragma unroll
        for (int j = 0; j < 4; ++j) {
            int lc = wn * 64 + j * 16 + l15;
#pragma unroll
            for (int r = 0; r < 4; ++r)
                gp[(lr0 + r) * 128 + lc] = acc[i][j][r];
        }
    }
}

// ---------------------------------------------------------------- kernel 2
// Reduce partials -> full symmetric G + per-row inverse norm. Zeroes out[0].
__global__ __launch_bounds__(256) void k_red(const float* __restrict__ Gp,
                                             float* __restrict__ G,
                                             float* __restrict__ invn,
                                             float* __restrict__ out) {
    int t    = blockIdx.x * 256 + threadIdx.x;
    if (t == 0) out[0] = 0.0f;
    int tile = t >> 14;
    int idx  = t & 16383;
    int lr   = idx >> 7, lc = idx & 127;
    const float* p = Gp + ((size_t)tile << 14) + idx;
    float s = 0.0f;
#pragma unroll 8
    for (int ks = 0; ks < KSPLIT; ++ks) s += p[(size_t)ks * 98304];
    int tm = (tile < 3) ? 0 : ((tile < 5) ? 1 : 2);
    int tn = (tile < 3) ? tile : ((tile < 5) ? (tile - 2) : 2);
    int a = tm * 128 + lr, b = tn * 128 + lc;
    G[(size_t)a * NR + b] = s;
    G[(size_t)b * NR + a] = s;
    if (a == b) invn[a] = 1.0f / fmaxf(sqrtf(s), 1e-6f);
}

// ---------------------------------------------------------------- kernel 3
// One wave per row a: Ds[a] = sum_b mask*exp(S[a][b]); then lane 0 adds this
// row's 4 pair-slot terms  (-num + log(exp(num)+Ds[a]))  to out.
// Slot partner table (derived from i1/i2/i3/i4 index algebra, verified):
//   a<16:        {192+a, a+16,  a+192, a+368}
//   16<=a<192:   {192+a, a+16,  a+192, a-16 }
//   192<=a<368:  {a-192, a+16,  a-192, a-16 }
//   a>=368:      {a-192, a-368, a-192, a-16 }
__global__ __launch_bounds__(256) void k_dsum(const float* __restrict__ G,
                                              const float* __restrict__ invn,
                                              float* __restrict__ out) {
    const int lane = threadIdx.x & 63;
    const int a    = blockIdx.x * 4 + (threadIdx.x >> 6);
    float ia  = invn[a];
    int arem  = a & 15;
    float acc = 0.0f;
    for (int b = lane; b < NR; b += 64) {
        float s = G[(size_t)a * NR + b] * ia * invn[b] * 10.0f;
        if ((b & 15) != arem) acc += expf(s);
    }
#pragma unroll
    for (int o = 32; o > 0; o >>= 1) acc += __shfl_down(acc, o);
    if (lane == 0) {
        float Dsa = acc;
        int pr[4];
        if (a < 16)       { pr[0] = 192 + a; pr[1] = a + 16;  pr[2] = a + 192; pr[3] = a + 368; }
        else if (a < 192) { pr[0] = 192 + a; pr[1] = a + 16;  pr[2] = a + 192; pr[3] = a - 16; }
        else if (a < 368) { pr[0] = a - 192; pr[1] = a + 16;  pr[2] = a - 192; pr[3] = a - 16; }
        else              { pr[0] = a - 192; pr[1] = a - 368; pr[2] = a - 192; pr[3] = a - 16; }
        float t = 0.0f;
#pragma unroll
        for (int s = 0; s < 4; ++s) {
            int b = pr[s];
            float num = G[(size_t)a * NR + b] * ia * invn[b] * 10.0f;
            t += -num + logf(expf(num) + Dsa);
        }
        atomicAdd(out, t * (1.0f / 576.0f));   // / (N_TRANSFORMS*3*BS)
    }
}

// ---------------------------------------------------------------- launch
extern "C" void kernel_launch(void* const* d_in, const int* in_sizes, int n_in,
                              void* d_out, int out_size, void* d_ws, size_t ws_size,
                              hipStream_t stream) {
    const float* X = (const float*)d_in[0];
    const float* M = (const float*)d_in[1];
    float* out = (float*)d_out;

    char* ws = (char*)d_ws;
    float* Gp   = (float*)ws;                                  // 50.3 MB
    float* G    = Gp + (size_t)KSPLIT * 6 * 16384;             // 590 KB
    float* invn = G + (size_t)NR * NR;

    k_gram<<<dim3(6 * KSPLIT), dim3(256), 0, stream>>>(X, M, Gp);
    k_red<<<dim3(384), dim3(256), 0, stream>>>(Gp, G, invn, out);
    k_dsum<<<dim3(NR / 4), dim3(256), 0, stream>>>(G, invn, out);
}